// Round 9
// baseline (825.521 us; speedup 1.0000x reference)
//
#include <hip/hip_runtime.h>
#include <math.h>

typedef __attribute__((ext_vector_type(8))) _Float16 half8;  // 8 fp16 = 4 VGPRs
typedef __attribute__((ext_vector_type(8))) short short8;
typedef __attribute__((ext_vector_type(4))) float float4v;

// ---------------- fp16 helpers ---------------------------------------------
static __device__ __forceinline__ unsigned short f2h(float f) {
  union { _Float16 h; unsigned short u; } c;
  c.h = (_Float16)f;
  return c.u;
}
static __device__ __forceinline__ float h2f(unsigned short u) {
  union { unsigned short u; _Float16 h; } c;
  c.u = u;
  return (float)c.h;
}

// ---------------------------------------------------------------------------
// split_x: elementwise x fp32 -> xh/xl fp16 (hi + residual), row-major.
// ---------------------------------------------------------------------------
__global__ __launch_bounds__(256)
void split_x(const float* __restrict__ x, unsigned short* __restrict__ xh,
             unsigned short* __restrict__ xl) {
  const size_t i = ((size_t)blockIdx.x * 256 + threadIdx.x) * 8;
  const float4 f0 = *(const float4*)(x + i);
  const float4 f1 = *(const float4*)(x + i + 4);
  const float fv[8] = {f0.x, f0.y, f0.z, f0.w, f1.x, f1.y, f1.z, f1.w};
  half8 hh, ll;
  #pragma unroll
  for (int j = 0; j < 8; ++j) {
    const _Float16 hb = (_Float16)fv[j];
    hh[j] = hb;
    ll[j] = (_Float16)(fv[j] - (float)hb);
  }
  *(half8*)(xh + i) = hh;
  *(half8*)(xl + i) = ll;
}

// ---------------------------------------------------------------------------
// split_pack: weights [nmat][K][N] fp32 -> packed swizzled fp16 hi/lo k-tiles.
// Layout: [mat][kt][N rows][32 halves], chunk (row,q) at q' = q ^ ((row>>1)&3).
// (Swizzle kept so the packed image stays byte-compatible with prior rounds;
//  direct reg loads simply address position q^((m>>1)&3).)
// ---------------------------------------------------------------------------
__global__ __launch_bounds__(256)
void split_pack(const float* __restrict__ src, unsigned short* __restrict__ dh,
                unsigned short* __restrict__ dl, int K, int N) {
  __shared__ float t[32][33];
  src += (size_t)blockIdx.z * K * N;
  const size_t tsz = (size_t)N * 32;  // ushorts per tile
  const size_t tb = ((size_t)blockIdx.z * (K >> 5) + blockIdx.x) * tsz;
  const int k0 = blockIdx.x * 32, n0 = blockIdx.y * 32;
  const int tid = threadIdx.x;
  const int r = tid >> 3, c4 = (tid & 7) * 4;

  const float4 v = *(const float4*)(src + (size_t)(k0 + r) * N + n0 + c4);
  t[r][c4 + 0] = v.x; t[r][c4 + 1] = v.y; t[r][c4 + 2] = v.z; t[r][c4 + 3] = v.w;
  __syncthreads();

  const int sel = tid >> 7;          // 0 = hi, 1 = lo
  const int rl = (tid >> 2) & 31;    // row within this 32-row slab
  const int qq = tid & 3;            // logical 16B chunk within row
  short8 vv;
  #pragma unroll
  for (int j = 0; j < 8; ++j) {
    const float f = t[qq * 8 + j][rl];
    const unsigned short hb = f2h(f);
    ((unsigned short*)&vv)[j] = sel ? f2h(f - h2f(hb)) : hb;
  }
  unsigned short* dst = (sel ? dl : dh) + tb +
      (size_t)(n0 + rl) * 32 + (qq ^ ((rl >> 1) & 3)) * 8;
  *(short8*)dst = vv;
}

// ---------------------------------------------------------------------------
// LN (+bias) + ReLU epilogue over N cols (4 waves, col-split), then store
// fp16 bits to dst[row * dstride + col]. Ends with a barrier.
// ---------------------------------------------------------------------------
template<int N, int NT>
__device__ __forceinline__ void ln_store_f16(
    float4v (*acc)[4], int w, int m, int q,
    const float* __restrict__ bias, const float* __restrict__ gamma,
    const float* __restrict__ beta,
    unsigned short* __restrict__ dst, int dstride,
    float (*sumP)[4], float (*sqP)[4]) {
  constexpr int NW = N / 4;
  float cb[NT], cg[NT], cbt[NT];
  #pragma unroll
  for (int t = 0; t < NT; ++t) {
    const int col = w * NW + t * 16 + m;
    cb[t] = bias[col]; cg[t] = gamma[col]; cbt[t] = beta[col];
  }
  #pragma unroll
  for (int s = 0; s < 4; ++s)
    #pragma unroll
    for (int r = 0; r < 4; ++r) {
      float s1 = 0.f, s2 = 0.f;
      #pragma unroll
      for (int t = 0; t < NT; ++t) {
        const float v = acc[s][t][r] + cb[t];
        s1 += v; s2 += v * v;
      }
      #pragma unroll
      for (int off = 1; off < 16; off <<= 1) {
        s1 += __shfl_xor(s1, off, 16);
        s2 += __shfl_xor(s2, off, 16);
      }
      if (m == 0) {
        sumP[s * 16 + q * 4 + r][w] = s1;
        sqP[s * 16 + q * 4 + r][w] = s2;
      }
    }
  __syncthreads();
  #pragma unroll
  for (int s = 0; s < 4; ++s)
    #pragma unroll
    for (int r = 0; r < 4; ++r) {
      const int row = s * 16 + q * 4 + r;
      const float S1 = sumP[row][0] + sumP[row][1] + sumP[row][2] + sumP[row][3];
      const float S2 = sqP[row][0] + sqP[row][1] + sqP[row][2] + sqP[row][3];
      const float mean = S1 * (1.f / N);
      const float var = S2 * (1.f / N) - mean * mean;
      const float inv = rsqrtf(var + 1e-5f);
      #pragma unroll
      for (int t = 0; t < NT; ++t) {
        const float o =
            fmaxf((acc[s][t][r] + cb[t] - mean) * inv * cg[t] + cbt[t], 0.f);
        dst[row * dstride + w * NW + t * 16 + m] = f2h(o);
      }
    }
  __syncthreads();
}

// ---------------------------------------------------------------------------
// Fused expert tower — LDS-FREE k-loops. Fragments have no cross-wave reuse
// (A is identical across waves, B is per-wave-exclusive), so all operands
// load global->register directly, 2-deep pipelined. Bit-identical MFMA order.
// LDS: hbuf (64x264 fp16) + sumP/sqP only. No barriers inside k-loops.
// ---------------------------------------------------------------------------
#define P1_STEP(KT, CAh, CAl, CBh, CBl, NAh, NAl, NBh, NBl)                    \
  {                                                                            \
    if ((KT) < 15) {                                                           \
      const unsigned short* bp =                                               \
          w1h + (size_t)(e * 16 + (KT) + 1) * 8192 + wB;                       \
      const unsigned short* bq =                                               \
          w1l + (size_t)(e * 16 + (KT) + 1) * 8192 + wB;                       \
      _Pragma("unroll") for (int t = 0; t < 4; ++t) {                          \
        NBh[t] = *(const half8*)(bp + t * 512);                                \
        NBl[t] = *(const half8*)(bq + t * 512);                                \
      }                                                                        \
      _Pragma("unroll") for (int s = 0; s < 4; ++s) {                          \
        NAh[s] = *(const half8*)(xph + s * 8192 + ((KT) + 1) * 32);            \
        NAl[s] = *(const half8*)(xpl + s * 8192 + ((KT) + 1) * 32);            \
      }                                                                        \
    }                                                                          \
    __builtin_amdgcn_s_setprio(1);                                             \
    _Pragma("unroll") for (int t = 0; t < 4; ++t) {                            \
      _Pragma("unroll") for (int s = 0; s < 4; ++s) {                          \
        acc[s][t] = __builtin_amdgcn_mfma_f32_16x16x32_f16(CAh[s], CBh[t], acc[s][t], 0, 0, 0); \
        acc[s][t] = __builtin_amdgcn_mfma_f32_16x16x32_f16(CAl[s], CBh[t], acc[s][t], 0, 0, 0); \
        acc[s][t] = __builtin_amdgcn_mfma_f32_16x16x32_f16(CAh[s], CBl[t], acc[s][t], 0, 0, 0); \
      }                                                                        \
    }                                                                          \
    __builtin_amdgcn_s_setprio(0);                                             \
  }

#define P2_STEP(KT, CBh, CBl, NBh, NBl)                                        \
  {                                                                            \
    if ((KT) < 7) {                                                            \
      const unsigned short* bp =                                               \
          w2h + (size_t)(e * 8 + (KT) + 1) * 8192 + wB;                        \
      const unsigned short* bq =                                               \
          w2l + (size_t)(e * 8 + (KT) + 1) * 8192 + wB;                        \
      _Pragma("unroll") for (int t = 0; t < 4; ++t) {                          \
        NBh[t] = *(const half8*)(bp + t * 512);                                \
        NBl[t] = *(const half8*)(bq + t * 512);                                \
      }                                                                        \
    }                                                                          \
    half8 ah[4];                                                               \
    _Pragma("unroll") for (int s = 0; s < 4; ++s)                              \
      ah[s] = *(const half8*)(hbuf + (s * 16 + m) * 264 + (KT) * 32 + q * 8);  \
    __builtin_amdgcn_s_setprio(1);                                             \
    _Pragma("unroll") for (int t = 0; t < 4; ++t) {                            \
      _Pragma("unroll") for (int s = 0; s < 4; ++s) {                          \
        acc[s][t] = __builtin_amdgcn_mfma_f32_16x16x32_f16(ah[s], CBh[t], acc[s][t], 0, 0, 0); \
        acc[s][t] = __builtin_amdgcn_mfma_f32_16x16x32_f16(ah[s], CBl[t], acc[s][t], 0, 0, 0); \
      }                                                                        \
    }                                                                          \
    __builtin_amdgcn_s_setprio(0);                                             \
  }

#define P3_STEP(KT, CBh, CBl, NBh, NBl)                                        \
  {                                                                            \
    if ((KT) < 7) {                                                            \
      const unsigned short* bp =                                               \
          w3h + (size_t)(e * 8 + (KT) + 1) * 4096 + wB3;                       \
      const unsigned short* bq =                                               \
          w3l + (size_t)(e * 8 + (KT) + 1) * 4096 + wB3;                       \
      _Pragma("unroll") for (int t = 0; t < 2; ++t) {                          \
        NBh[t] = *(const half8*)(bp + t * 512);                                \
        NBl[t] = *(const half8*)(bq + t * 512);                                \
      }                                                                        \
    }                                                                          \
    half8 ah[4];                                                               \
    _Pragma("unroll") for (int s = 0; s < 4; ++s)                              \
      ah[s] = *(const half8*)(hbuf + (s * 16 + m) * 264 + (KT) * 32 + q * 8);  \
    __builtin_amdgcn_s_setprio(1);                                             \
    _Pragma("unroll") for (int t = 0; t < 2; ++t) {                            \
      _Pragma("unroll") for (int s = 0; s < 4; ++s) {                          \
        acc[s][t] = __builtin_amdgcn_mfma_f32_16x16x32_f16(ah[s], CBh[t], acc[s][t], 0, 0, 0); \
        acc[s][t] = __builtin_amdgcn_mfma_f32_16x16x32_f16(ah[s], CBl[t], acc[s][t], 0, 0, 0); \
      }                                                                        \
    }                                                                          \
    __builtin_amdgcn_s_setprio(0);                                             \
  }

__global__ __launch_bounds__(256, 2)
void expert_tower(const unsigned short* __restrict__ xh,
                  const unsigned short* __restrict__ xl,
                  const unsigned short* __restrict__ w1h,
                  const unsigned short* __restrict__ w1l,
                  const float* __restrict__ eb1, const float* __restrict__ eg1,
                  const float* __restrict__ ebt1,
                  const unsigned short* __restrict__ w2h,
                  const unsigned short* __restrict__ w2l,
                  const float* __restrict__ eb2, const float* __restrict__ eg2,
                  const float* __restrict__ ebt2,
                  const unsigned short* __restrict__ w3h,
                  const unsigned short* __restrict__ w3l,
                  const float* __restrict__ eb3, const float* __restrict__ eg3,
                  const float* __restrict__ ebt3,
                  unsigned short* __restrict__ eo, int B) {
  __shared__ __align__(16) unsigned short hbuf[16896];  // 64 x 264 fp16
  __shared__ float sumP[64][4];
  __shared__ float sqP[64][4];

  const int tid = threadIdx.x;
  const int w = tid >> 6, lane = tid & 63, m = lane & 15, q = lane >> 4;
  const int qs8 = (q ^ ((m >> 1) & 3)) * 8;  // packed-image chunk position
  const int m0 = blockIdx.x * 64;
  const int e = blockIdx.y;

  // per-lane operand bases
  const unsigned short* xph = xh + (size_t)(m0 + m) * 512 + q * 8;
  const unsigned short* xpl = xl + (size_t)(m0 + m) * 512 + q * 8;
  const int wB = (w * 64 + m) * 32 + qs8;   // P1/P2 B fragment base
  const int wB3 = (w * 32 + m) * 32 + qs8;  // P3 B fragment base

  eb1 += (size_t)e * 256; eg1 += (size_t)e * 256; ebt1 += (size_t)e * 256;
  eb2 += (size_t)e * 256; eg2 += (size_t)e * 256; ebt2 += (size_t)e * 256;
  eb3 += (size_t)e * 128; eg3 += (size_t)e * 128; ebt3 += (size_t)e * 128;

  float4v acc[4][4];

  // ========== phase 1: K=512, N=256, 3-term, regs only ======================
  #pragma unroll
  for (int s = 0; s < 4; ++s)
    #pragma unroll
    for (int t = 0; t < 4; ++t) acc[s][t] = (float4v){0.f, 0.f, 0.f, 0.f};

  half8 A0h[4], A0l[4], B0h[4], B0l[4];
  half8 A1h[4], A1l[4], B1h[4], B1l[4];
  {  // prologue: load tile 0 into set0
    const unsigned short* bp = w1h + (size_t)(e * 16) * 8192 + wB;
    const unsigned short* bq = w1l + (size_t)(e * 16) * 8192 + wB;
    #pragma unroll
    for (int t = 0; t < 4; ++t) {
      B0h[t] = *(const half8*)(bp + t * 512);
      B0l[t] = *(const half8*)(bq + t * 512);
    }
    #pragma unroll
    for (int s = 0; s < 4; ++s) {
      A0h[s] = *(const half8*)(xph + s * 8192);
      A0l[s] = *(const half8*)(xpl + s * 8192);
    }
  }
  for (int kt = 0; kt < 16; kt += 2) {
    P1_STEP(kt,     A0h, A0l, B0h, B0l, A1h, A1l, B1h, B1l);
    P1_STEP(kt + 1, A1h, A1l, B1h, B1l, A0h, A0l, B0h, B0l);
  }
  ln_store_f16<256, 4>(acc, w, m, q, eb1, eg1, ebt1, hbuf, 264, sumP, sqP);

  // ========== phase 2: K=256, N=256, 2-term, B regs + hbuf A ================
  #pragma unroll
  for (int s = 0; s < 4; ++s)
    #pragma unroll
    for (int t = 0; t < 4; ++t) acc[s][t] = (float4v){0.f, 0.f, 0.f, 0.f};

  {
    const unsigned short* bp = w2h + (size_t)(e * 8) * 8192 + wB;
    const unsigned short* bq = w2l + (size_t)(e * 8) * 8192 + wB;
    #pragma unroll
    for (int t = 0; t < 4; ++t) {
      B0h[t] = *(const half8*)(bp + t * 512);
      B0l[t] = *(const half8*)(bq + t * 512);
    }
  }
  for (int kt = 0; kt < 8; kt += 2) {
    P2_STEP(kt,     B0h, B0l, B1h, B1l);
    P2_STEP(kt + 1, B1h, B1l, B0h, B0l);
  }
  ln_store_f16<256, 4>(acc, w, m, q, eb2, eg2, ebt2, hbuf, 264, sumP, sqP);

  // ========== phase 3: K=256, N=128, 2-term, B regs + hbuf A ================
  #pragma unroll
  for (int s = 0; s < 4; ++s)
    #pragma unroll
    for (int t = 0; t < 2; ++t) acc[s][t] = (float4v){0.f, 0.f, 0.f, 0.f};

  {
    const unsigned short* bp = w3h + (size_t)(e * 8) * 4096 + wB3;
    const unsigned short* bq = w3l + (size_t)(e * 8) * 4096 + wB3;
    #pragma unroll
    for (int t = 0; t < 2; ++t) {
      B0h[t] = *(const half8*)(bp + t * 512);
      B0l[t] = *(const half8*)(bq + t * 512);
    }
  }
  for (int kt = 0; kt < 8; kt += 2) {
    P3_STEP(kt,     B0h, B0l, B1h, B1l);
    P3_STEP(kt + 1, B1h, B1l, B0h, B0l);
  }
  // epilogue 3 -> repack buffer (stride 136, overlays hbuf head) -> eo
  unsigned short* rp = hbuf;
  ln_store_f16<128, 2>(acc, w, m, q, eb3, eg3, ebt3, rp, 136, sumP, sqP);
  #pragma unroll
  for (int i = 0; i < 4; ++i) {
    const int c = tid + i * 256;
    const int rowc = c >> 4, c8 = c & 15;
    *(short8*)(eo + ((size_t)e * B + m0 + rowc) * 128 + c8 * 8) =
        *(const short8*)(rp + rowc * 136 + c8 * 8);
  }
}

// ---------------------------------------------------------------------------
// Gating GEMM + fused gate2, LDS-free k-loop (same direct-reg scheme).
// ---------------------------------------------------------------------------
#define G_STEP(KT, CAh, CAl, CBh, CBl, NAh, NAl, NBh, NBl)                     \
  {                                                                            \
    if ((KT) < 15) {                                                           \
      const size_t tb = (size_t)(slice * 16 + (KT) + 1) * 2048 + wB;           \
      NBh = *(const half8*)(twh + tb);                                         \
      NBl = *(const half8*)(twl + tb);                                         \
      _Pragma("unroll") for (int s = 0; s < 4; ++s) {                          \
        NAh[s] = *(const half8*)(xph + s * 8192 + ((KT) + 1) * 32);            \
        NAl[s] = *(const half8*)(xpl + s * 8192 + ((KT) + 1) * 32);            \
      }                                                                        \
    }                                                                          \
    __builtin_amdgcn_s_setprio(1);                                             \
    _Pragma("unroll") for (int s = 0; s < 4; ++s) {                            \
      acc[s] = __builtin_amdgcn_mfma_f32_16x16x32_f16(CAh[s], CBh, acc[s], 0, 0, 0); \
      acc[s] = __builtin_amdgcn_mfma_f32_16x16x32_f16(CAl[s], CBh, acc[s], 0, 0, 0); \
      acc[s] = __builtin_amdgcn_mfma_f32_16x16x32_f16(CAh[s], CBl, acc[s], 0, 0, 0); \
    }                                                                          \
    __builtin_amdgcn_s_setprio(0);                                             \
  }

template<int NOUT>
__global__ __launch_bounds__(256, 4)
void gate_gemm(const unsigned short* __restrict__ xh,
               const unsigned short* __restrict__ xl,
               const unsigned short* __restrict__ twh,
               const unsigned short* __restrict__ twl,
               const float* __restrict__ b1, const float* __restrict__ w2,
               const float* __restrict__ b2, float* __restrict__ outw,
               int slice_base, int B) {
  __shared__ float ghs[64][65];
  __shared__ float wls[64 * NOUT];
  __shared__ float bls[NOUT];

  const int tid = threadIdx.x;
  const int w = tid >> 6, lane = tid & 63, m = lane & 15, q = lane >> 4;
  const int qs8 = (q ^ ((m >> 1) & 3)) * 8;
  const int m0 = blockIdx.x * 64;
  const int slice = slice_base + blockIdx.y;
  const unsigned short* xph = xh + (size_t)(m0 + m) * 512 + q * 8;
  const unsigned short* xpl = xl + (size_t)(m0 + m) * 512 + q * 8;
  const int wB = (w * 16 + m) * 32 + qs8;
  const float* bias = b1 + (size_t)blockIdx.y * 64;
  const float* w2p = w2 + (size_t)blockIdx.y * 64 * NOUT;
  const float* b2p = b2 + (size_t)blockIdx.y * NOUT;
  float* outp = outw + (size_t)blockIdx.y * B * NOUT;

  float4v acc[4];
  #pragma unroll
  for (int s = 0; s < 4; ++s) acc[s] = (float4v){0.f, 0.f, 0.f, 0.f};

  half8 A0h[4], A0l[4], A1h[4], A1l[4];
  half8 B0h, B0l, B1h, B1l;
  {
    const size_t tb = (size_t)(slice * 16) * 2048 + wB;
    B0h = *(const half8*)(twh + tb);
    B0l = *(const half8*)(twl + tb);
    #pragma unroll
    for (int s = 0; s < 4; ++s) {
      A0h[s] = *(const half8*)(xph + s * 8192);
      A0l[s] = *(const half8*)(xpl + s * 8192);
    }
  }
  for (int kt = 0; kt < 16; kt += 2) {
    G_STEP(kt,     A0h, A0l, B0h, B0l, A1h, A1l, B1h, B1l);
    G_STEP(kt + 1, A1h, A1l, B1h, B1l, A0h, A0l, B0h, B0l);
  }

  // ---- fused gate2 epilogue ----
  const float cb = bias[w * 16 + m];
  #pragma unroll
  for (int s = 0; s < 4; ++s)
    #pragma unroll
    for (int r = 0; r < 4; ++r)
      ghs[s * 16 + q * 4 + r][w * 16 + m] = fmaxf(acc[s][r] + cb, 0.f);
  for (int f = tid; f < 64 * NOUT; f += 256) wls[f] = w2p[f];
  if (tid < NOUT) bls[tid] = b2p[tid];
  __syncthreads();

  if (tid < 64) {
    float a[NOUT];
    #pragma unroll
    for (int n = 0; n < NOUT; ++n) a[n] = bls[n];
    for (int k = 0; k < 64; ++k) {
      const float g = ghs[tid][k];
      #pragma unroll
      for (int n = 0; n < NOUT; ++n) a[n] = fmaf(g, wls[k * NOUT + n], a[n]);
    }
    float mx = a[0];
    #pragma unroll
    for (int n = 1; n < NOUT; ++n) mx = fmaxf(mx, a[n]);
    float sum = 0.f;
    #pragma unroll
    for (int n = 0; n < NOUT; ++n) { a[n] = expf(a[n] - mx); sum += a[n]; }
    const float r = 1.f / sum;
    #pragma unroll
    for (int n = 0; n < NOUT; ++n)
      outp[(size_t)(m0 + tid) * NOUT + n] = a[n] * r;
  }
}

// ---------------------------------------------------------------------------
// Final combine: out[s][b][:] = sum_e coef(s,e,b) * eo[e][b][:]  (eo fp16)
// ---------------------------------------------------------------------------
__global__ __launch_bounds__(256)
void combine(const unsigned short* __restrict__ eo, const float* __restrict__ gw,
             const float* __restrict__ sgw, float* __restrict__ out, int B) {
  const int tid = threadIdx.x;
  const int gb = blockIdx.x * 16 + (tid >> 4);
  const int c0 = (tid & 15) * 8;

  float a[4][8];
  #pragma unroll
  for (int s = 0; s < 4; ++s)
    #pragma unroll
    for (int i = 0; i < 8; ++i) a[s][i] = 0.f;

  #pragma unroll
  for (int e = 0; e < 10; ++e) {
    const half8 vv = *(const half8*)(eo + ((size_t)e * B + gb) * 128 + c0);
    float f[8];
    #pragma unroll
    for (int i = 0; i < 8; ++i) f[i] = (float)vv[i];
    float c[4];
    c[3] = sgw[(size_t)gb * 10 + e];
    c[0] = c[1] = c[2] = 0.f;
    if (e < 4) {
      c[0] = gw[((size_t)0 * B + gb) * 6 + e];
      c[1] = gw[((size_t)1 * B + gb) * 6 + e];
      c[2] = gw[((size_t)2 * B + gb) * 6 + e];
    } else {
      const int tt = (e - 4) >> 1;
      c[tt] = gw[((size_t)tt * B + gb) * 6 + 4 + ((e - 4) & 1)];
    }
    #pragma unroll
    for (int s = 0; s < 4; ++s)
      #pragma unroll
      for (int i = 0; i < 8; ++i) a[s][i] = fmaf(c[s], f[i], a[s][i]);
  }

  #pragma unroll
  for (int s = 0; s < 4; ++s) {
    float* p = out + ((size_t)s * B + gb) * 128 + c0;
    const float4 v0 = {a[s][0], a[s][1], a[s][2], a[s][3]};
    const float4 v1 = {a[s][4], a[s][5], a[s][6], a[s][7]};
    *(float4*)p = v0;
    *(float4*)(p + 4) = v1;
  }
}

// ---------------------------------------------------------------------------
extern "C" void kernel_launch(void* const* d_in, const int* in_sizes, int n_in,
                              void* d_out, int out_size, void* d_ws, size_t ws_size,
                              hipStream_t stream) {
  const float* x     = (const float*)d_in[0];
  const float* ew1   = (const float*)d_in[1];
  const float* eb1   = (const float*)d_in[2];
  const float* eg1   = (const float*)d_in[3];
  const float* ebt1  = (const float*)d_in[4];
  const float* ew2   = (const float*)d_in[5];
  const float* eb2   = (const float*)d_in[6];
  const float* eg2   = (const float*)d_in[7];
  const float* ebt2  = (const float*)d_in[8];
  const float* ew3   = (const float*)d_in[9];
  const float* eb3   = (const float*)d_in[10];
  const float* eg3   = (const float*)d_in[11];
  const float* ebt3  = (const float*)d_in[12];
  const float* tg_w1 = (const float*)d_in[13];
  const float* tg_b1 = (const float*)d_in[14];
  const float* tg_w2 = (const float*)d_in[15];
  const float* tg_b2 = (const float*)d_in[16];
  const float* sg_w1 = (const float*)d_in[17];
  const float* sg_b1 = (const float*)d_in[18];
  const float* sg_w2 = (const float*)d_in[19];
  const float* sg_b2 = (const float*)d_in[20];
  float* out = (float*)d_out;

  const int B = 32768, D = 512, H = 256, O = 128, G = 64, E = 10;
  (void)D; (void)H; (void)O; (void)G;

  // ---- workspace: weights ~53MB + gwb/sgwb + eo 84MB + xh/xl 64MB ----
  char* p = (char*)d_ws;
  unsigned short* w1h  = (unsigned short*)p; p += (size_t)E * 16 * 8192 * 2;
  unsigned short* w1l  = (unsigned short*)p; p += (size_t)E * 16 * 8192 * 2;
  unsigned short* w2h  = (unsigned short*)p; p += (size_t)E * 8 * 8192 * 2;
  unsigned short* w2l  = (unsigned short*)p; p += (size_t)E * 8 * 8192 * 2;
  unsigned short* w3h  = (unsigned short*)p; p += (size_t)E * 8 * 4096 * 2;
  unsigned short* w3l  = (unsigned short*)p; p += (size_t)E * 8 * 4096 * 2;
  unsigned short* twh  = (unsigned short*)p; p += (size_t)4 * 16 * 2048 * 2;
  unsigned short* twl  = (unsigned short*)p; p += (size_t)4 * 16 * 2048 * 2;
  float* gwb  = (float*)p; p += (size_t)3 * B * 6 * 4;
  float* sgwb = (float*)p; p += (size_t)B * 10 * 4;
  unsigned short* eo = (unsigned short*)p; p += (size_t)E * B * 128 * 2;
  unsigned short* xh = (unsigned short*)p; p += (size_t)B * 512 * 2;
  unsigned short* xl = (unsigned short*)p;

  // ---- 1. conversions: x split (once) + weights (fp16 split, packed) ----
  split_x<<<B * 512 / (256 * 8), 256, 0, stream>>>(x, xh, xl);
  split_pack<<<dim3(16, 8, E), 256, 0, stream>>>(ew1, w1h, w1l, 512, 256);
  split_pack<<<dim3(8, 8, E), 256, 0, stream>>>(ew2, w2h, w2l, 256, 256);
  split_pack<<<dim3(8, 4, E), 256, 0, stream>>>(ew3, w3h, w3l, 256, 128);
  split_pack<<<dim3(16, 2, 3), 256, 0, stream>>>(tg_w1, twh, twl, 512, 64);
  split_pack<<<dim3(16, 2, 1), 256, 0, stream>>>(
      sg_w1, twh + (size_t)3 * 16 * 2048, twl + (size_t)3 * 16 * 2048, 512, 64);

  // ---- 2. gating (gate2 fused into the GEMM epilogue) ----
  gate_gemm<6><<<dim3(B / 64, 3), 256, 0, stream>>>(
      xh, xl, twh, twl, tg_b1, tg_w2, tg_b2, gwb, 0, B);
  gate_gemm<10><<<dim3(B / 64, 1), 256, 0, stream>>>(
      xh, xl, twh, twl, sg_b1, sg_w2, sg_b2, sgwb, 3, B);

  // ---- 3. fused expert towers: one launch, all experts ----
  expert_tower<<<dim3(B / 64, E), 256, 0, stream>>>(
      xh, xl, w1h, w1l, eb1, eg1, ebt1, w2h, w2l, eb2, eg2, ebt2,
      w3h, w3l, eb3, eg3, ebt3, eo, B);

  // ---- 4. combine ----
  combine<<<B / 16, 256, 0, stream>>>(eo, gwb, sgwb, out, B);
}